// Round 8
// baseline (253.296 us; speedup 1.0000x reference)
//
#include <hip/hip_runtime.h>
#include <hip/hip_bf16.h>

// Attention forward, MI355X (gfx950). fp32 in/out, bf16 MFMA internally.
// ws (56 MB): wqkv_b[3072x1024 bf16] | wo_b[1024x1024 bf16] | QKV[8192x3072 bf16]
// xb (bf16 x) lives in d_out's first 16 MB (dead before out-proj writes).
// Dispatches: 1 fused convert; QKV GEMM; flash; out-proj GEMM.
// MFMA layouts (verified m89/m74):
//   A-frag: A[m=lane&15][k=(lane>>4)*8+j]; B-frag: B[n=lane&15][k=...]
//   C/D:    col=lane&15, row=(lane>>4)*4+reg
//
// Round-8:  both-sides LDS swizzles in flash. Conflicts 1.62e7->6.5e6, dur flat.
// Round-9:  lgkm-only barrier in flash. 163->157 us.
// Round-10: K LDS-staged (pre-swizzled source) + XCD grouping in flash.
//           FETCH 240->38 MB, flash 157->89.6 us. Latency theory confirmed.
// Round-11: GEMM XCD remap + BK=64 swizzled staging + fused converts. 280->262.
// Round-12: fused pair p-loop: np non-uniform per CU -> 105 us. REVERTED.
// Round-13: revert + ones-MFMA l-sum + setprio: flash 86.3 us, VGPR 84.
// Round-14: gemm3 (128x256, 3-buf, 144 KB LDS, counted vmcnt): -13.6 us but
//           1 block/CU (no TLP) + 3 grid rounds capped the gain.
// Round-15 (this): BOTH GEMMs -> gemm2p: 128x128, BK=64, 4 waves, TWO LDS
//   buffers (64 KB -> 2 blocks/CU). T3-minimum schedule, NO vmcnt(0) in the
//   main loop: stage(t+1) | vmcnt(8) | barrier | 16 ds_read | lgkm0+barrier |
//   32 MFMA (setprio). Buf overwrite is provably after all reads (barrier2);
//   tile-t visibility from per-wave vmcnt(8) + barrier1. Staging/swizzle
//   identical to round-11 (proven). gemm3 removed. Flash untouched.

typedef short short8 __attribute__((ext_vector_type(8)));
typedef float f32x4 __attribute__((ext_vector_type(4)));

#define MFMA16(a, b, c) __builtin_amdgcn_mfma_f32_16x16x32_bf16((a), (b), (c), 0, 0, 0)

static __device__ __forceinline__ ushort f2bf(float f) {
  union { __hip_bfloat16 h; ushort u; } cv;
  cv.h = __float2bfloat16(f);
  return cv.u;
}

static __device__ __forceinline__ float fexp2(float x) {
#if __has_builtin(__builtin_amdgcn_exp2f)
  return __builtin_amdgcn_exp2f(x);
#else
  return __expf(x * 0.69314718056f);
#endif
}

// Barrier WITHOUT any vmcnt drain: LDS writes visible, globals keep flying.
static __device__ __forceinline__ void block_sync_lds() {
  asm volatile("s_waitcnt lgkmcnt(0)" ::: "memory");
  __builtin_amdgcn_s_barrier();
  __builtin_amdgcn_sched_barrier(0);
}

// Barrier that ALSO waits outstanding globals (global_load_lds visibility).
static __device__ __forceinline__ void block_sync_full() {
  asm volatile("s_waitcnt vmcnt(0) lgkmcnt(0)" ::: "memory");
  __builtin_amdgcn_s_barrier();
  __builtin_amdgcn_sched_barrier(0);
}

static __device__ __forceinline__ void store_out(float* p, float v) { *p = v; }
static __device__ __forceinline__ void store_out(__hip_bfloat16* p, float v) {
  *p = __float2bfloat16(v);
}

// One fused convert: wq|wk|wv -> wqkv_b rows, wo -> wo_b, x -> xb.
__global__ __launch_bounds__(256) void convert_all_kernel(
    const float* __restrict__ wq, const float* __restrict__ wk,
    const float* __restrict__ wv, const float* __restrict__ wo,
    const float* __restrict__ x, ushort* __restrict__ wqkv,
    ushort* __restrict__ wob, ushort* __restrict__ xb) {
  constexpr int W4 = 262144;           // (1024*1024)/4
  constexpr size_t WSZ = (size_t)1024 * 1024;
  const int i = blockIdx.x * blockDim.x + threadIdx.x;
  const float* src;
  ushort* dst;
  int j;
  if (i < 2 * W4) {
    if (i < W4)      { src = wq; dst = wqkv;           j = i; }
    else             { src = wk; dst = wqkv + WSZ;     j = i - W4; }
  } else if (i < 4 * W4) {
    if (i < 3 * W4)  { src = wv; dst = wqkv + 2 * WSZ; j = i - 2 * W4; }
    else             { src = wo; dst = wob;            j = i - 3 * W4; }
  } else {
    src = x; dst = xb; j = i - 4 * W4;
  }
  const float4 v = ((const float4*)src)[j];
  ushort4 o;
  o.x = f2bf(v.x); o.y = f2bf(v.y); o.z = f2bf(v.z); o.w = f2bf(v.w);
  ((ushort4*)dst)[j] = o;
}

// ---------------- 2-buffer pipelined 128x128 GEMM (gemm2p) ----------------
// C[M,N] = A[M,K](bf16) * B[N,K]^T(bf16), OUT_T out. BK=64, 4 waves,
// wave tile 64x64 (4x4 frags), 2 LDS buffers (64 KB -> 2 blocks/CU).
// Stage via global_load_lds w16, PRE-SWIZZLED SOURCE (rule 21): element
// (r, chunk c) lands at phys chunk c^(r&7); fragment reads conflict-free.
// Schedule (T3-min, counted vmcnt): per body, stage next tile into the other
// buffer, wait OWN vmcnt(8) (tile-t loads landed, t+1's 8 flying), barrier,
// read all 16 frags, lgkm0+barrier (reads done -> overwrite safe), 32 MFMA.
// XCD remap: id&7 = XCD owns cpx N-tiles; consecutive local ids share A-panel.
template <typename OUT_T>
__global__ __launch_bounds__(256, 2) void gemm_kernel(
    const ushort* __restrict__ A, int lda, const ushort* __restrict__ B, int ldb,
    OUT_T* __restrict__ C, int ldc, int K, int cpx) {
  __shared__ __align__(16) ushort As[2][128 * 64];
  __shared__ __align__(16) ushort Bs[2][128 * 64];
  const int tid = threadIdx.x;
  const int wave = tid >> 6, lane = tid & 63;
  const int lm = lane & 15, quad = lane >> 4;

  const int id = blockIdx.x;
  const int local = id >> 3;
  const int nt = (id & 7) * cpx + local % cpx;
  const int mt = local / cpx;
  const size_t m0 = (size_t)mt * 128;
  const size_t n0 = (size_t)nt * 128;

  const int rl = lane >> 3;        // row within 8-row staging chunk
  const int cs = (lane & 7) ^ rl;  // pre-swizzled source col-chunk
  const int fsw = lm & 7;          // fragment read swizzle key
  const int wm = (wave >> 1) * 64, wn = (wave & 1) * 64;
  const int T = K >> 6;

  // prologue: stage tile 0 -> buf 0 (8 loads/wave)
#pragma unroll
  for (int j = 0; j < 4; ++j) {
    const int ch = wave * 4 + j;
    __builtin_amdgcn_global_load_lds(
        (const __attribute__((address_space(1))) void*)(B + (n0 + ch * 8 + rl) * (size_t)ldb + cs * 8),
        (__attribute__((address_space(3))) void*)(Bs[0] + ch * 512), 16, 0, 0);
    __builtin_amdgcn_global_load_lds(
        (const __attribute__((address_space(1))) void*)(A + (m0 + ch * 8 + rl) * (size_t)lda + cs * 8),
        (__attribute__((address_space(3))) void*)(As[0] + ch * 512), 16, 0, 0);
  }

  f32x4 acc[4][4] = {};
  for (int t = 0; t < T; ++t) {
    const int cur = t & 1;
    // stage t+1 into the other buffer (last read in body t-1; all waves past
    // body t-1's barrier2 -> no overwrite race), then wait own tile-t loads.
    if (t + 1 < T) {
      const int k0 = (t + 1) << 6;
      ushort* an = As[cur ^ 1];
      ushort* bn = Bs[cur ^ 1];
#pragma unroll
      for (int j = 0; j < 4; ++j) {
        const int ch = wave * 4 + j;
        __builtin_amdgcn_global_load_lds(
            (const __attribute__((address_space(1))) void*)(B + (n0 + ch * 8 + rl) * (size_t)ldb + k0 + cs * 8),
            (__attribute__((address_space(3))) void*)(bn + ch * 512), 16, 0, 0);
        __builtin_amdgcn_global_load_lds(
            (const __attribute__((address_space(1))) void*)(A + (m0 + ch * 8 + rl) * (size_t)lda + k0 + cs * 8),
            (__attribute__((address_space(3))) void*)(an + ch * 512), 16, 0, 0);
      }
      asm volatile("s_waitcnt vmcnt(8)" ::: "memory");
    } else {
      asm volatile("s_waitcnt vmcnt(0)" ::: "memory");
    }
    __builtin_amdgcn_s_barrier();       // barrier1: tile t visible to all
    __builtin_amdgcn_sched_barrier(0);

    // read ALL fragments of tile t into regs
    short8 a[4][2], b[4][2];
    const ushort* ab = As[cur];
    const ushort* bb = Bs[cur];
#pragma unroll
    for (int i = 0; i < 4; ++i) {
      const ushort* ar = ab + (wm + i * 16 + lm) * 64;
      const ushort* br = bb + (wn + i * 16 + lm) * 64;
#pragma unroll
      for (int ks = 0; ks < 2; ++ks) {
        const int off = (((ks * 4 + quad) ^ fsw) & 7) << 3;
        a[i][ks] = *(const short8*)(ar + off);
        b[i][ks] = *(const short8*)(br + off);
      }
    }
    asm volatile("s_waitcnt lgkmcnt(0)" ::: "memory");
    __builtin_amdgcn_s_barrier();       // barrier2: all reads done
    __builtin_amdgcn_sched_barrier(0);

    __builtin_amdgcn_s_setprio(1);
#pragma unroll
    for (int i = 0; i < 4; ++i)
#pragma unroll
      for (int j = 0; j < 4; ++j)
#pragma unroll
        for (int ks = 0; ks < 2; ++ks)
          acc[i][j] = MFMA16(a[i][ks], b[j][ks], acc[i][j]);
    __builtin_amdgcn_s_setprio(0);
  }

  const int rq = quad * 4;
#pragma unroll
  for (int i = 0; i < 4; ++i)
#pragma unroll
    for (int j = 0; j < 4; ++j)
#pragma unroll
      for (int r = 0; r < 4; ++r)
        store_out(&C[(m0 + wm + i * 16 + rq + r) * (size_t)ldc + n0 + wn + j * 16 + lm],
                  acc[i][j][r]);
}

// Swizzled V^T LDS write: 8 cols starting at h0 for row p.
// Element (p, h) lives at h*64 + (((p>>3) ^ (h>>3) ^ (h&7)) & 7)*8 + (p&7).
static __device__ __forceinline__ void vt_write8(ushort* vtbuf, int h0, int hsw,
                                                 int p, const short8& v) {
  const int pc = (p >> 3) ^ hsw;
  ushort* row = vtbuf + h0 * 64 + (p & 7);
#pragma unroll
  for (int u = 0; u < 8; ++u)
    row[u * 64 + (((pc ^ u) & 7) << 3)] = ((const ushort*)&v)[u];
}

// Stage a 64x64 bf16 K tile (global rows pbase..pbase+63) into kbuf via
// global_load_lds, pre-swizzled source (rule 21).
static __device__ __forceinline__ void stage_k(const ushort* kglob, int pbase,
                                               ushort* kbuf, int wave, int lane) {
  const int rl = lane >> 3;           // row within the 8-row chunk (== r&7)
  const int c = (lane & 7) ^ rl;      // inverse-swizzled source chunk
#pragma unroll
  for (int j = 0; j < 2; ++j) {
    const int ch = wave * 2 + j;
    const ushort* src = kglob + (size_t)(pbase + ch * 8 + rl) * 3072 + c * 8;
    __builtin_amdgcn_global_load_lds(
        (const __attribute__((address_space(1))) void*)src,
        (__attribute__((address_space(3))) void*)(kbuf + ch * 512), 16, 0, 0);
  }
}

// Flash causal attention (round-4 structure + round-13 micros; verified 86.3).
__global__ __launch_bounds__(256) void flash4_kernel(ushort* __restrict__ QKV) {
  constexpr int LD = 3072;
  __shared__ __align__(16) ushort vt[2][64 * 64];
  __shared__ __align__(16) ushort kt[2][64 * 64];
  __shared__ __align__(16) ushort pbuf[4][16 * 64];

  const int id = blockIdx.x;
  const int g = (id & 7) * 8 + ((id >> 3) & 7);  // (b,head) group, XCD-local
  const int m = id >> 6;                          // q-pair index 0..15
  const int head = g & 15;
  const int b = g >> 4;

  const int tid = threadIdx.x;
  const int wave = tid >> 6, lane = tid & 63;
  const int lm = lane & 15, quad = lane >> 4;

  const size_t qcol = (size_t)b * 2048 * LD + head * 64;
  const size_t vcol = qcol + 2048;
  const ushort* kglob = QKV + qcol + 1024;

  const int h0 = (tid & 7) * 8;  // V staging: 8 cols per thread
  const int hsw = tid & 7;
  const int plb = tid >> 3;      // V staging p base (0..31)
  const int psw = lm & 7;        // pbuf row swizzle key
  const int ksw = lm & 7;        // kt fragment swizzle key

  constexpr float CSC = 0.180336880f;  // log2(e)/8
  const short8 vone = {0x3F80, 0x3F80, 0x3F80, 0x3F80,
                       0x3F80, 0x3F80, 0x3F80, 0x3F80};  // bf16 1.0 x8

  for (int pass = 0; pass < 2; ++pass) {
    const int qbi = pass ? 31 - m : m;
    const int qrow = qbi * 64 + wave * 16;
    const int qg = qrow + lm;
    const int nt = qbi + 1;

    const ushort* qp = QKV + qcol + (size_t)(qrow + lm) * LD;
    short8 qa0 = *(const short8*)(qp + quad * 8);
    short8 qa1 = *(const short8*)(qp + 32 + quad * 8);

    f32x4 accz[4] = {};   // Z C-layout: row q=quad*4+r, col h=c*16+lm
    f32x4 lacc = {};      // row-sum via ones-MFMA

    block_sync_lds();  // prior pass's vt/kt reads complete before restage

    stage_k(kglob, 0, kt[0], wave, lane);
#pragma unroll
    for (int rr = 0; rr < 2; ++rr) {
      const int p = plb + rr * 32;
      short8 v = *(const short8*)(QKV + vcol + (size_t)p * LD + h0);
      vt_write8(vt[0], h0, hsw, p, v);
    }

    for (int it = 0; it < nt; ++it) {
      const int p0 = it * 64;
      block_sync_full();

      short8 ka[4], kb[4];
      const ushort* kbuf = kt[it & 1];
#pragma unroll
      for (int s = 0; s < 4; ++s) {
        const ushort* kr = kbuf + (s * 16 + lm) * 64;
        ka[s] = *(const short8*)(kr + (((quad ^ ksw) & 7) << 3));
        kb[s] = *(const short8*)(kr + ((((quad + 4) ^ ksw) & 7) << 3));
      }

      const bool more = (it + 1 < nt);
      short8 nv0, nv1;
      if (more) {
        nv0 = *(const short8*)(QKV + vcol + (size_t)(p0 + 64 + plb) * LD + h0);
        nv1 = *(const short8*)(QKV + vcol + (size_t)(p0 + 96 + plb) * LD + h0);
        stage_k(kglob, p0 + 64, kt[(it + 1) & 1], wave, lane);
      }

      f32x4 t4[4];
      __builtin_amdgcn_s_setprio(1);
#pragma unroll
      for (int s = 0; s < 4; ++s) {
        f32x4 t = {0.f, 0.f, 0.f, 0.f};
        t = MFMA16(ka[s], qa0, t);
        t = MFMA16(kb[s], qa1, t);
        t4[s] = t;
      }
      __builtin_amdgcn_s_setprio(0);

      float ps[4][4];
      if (it != nt - 1) {
#pragma unroll
        for (int s = 0; s < 4; ++s)
#pragma unroll
          for (int r = 0; r < 4; ++r)
            ps[s][r] = fexp2(t4[s][r] * CSC);
      } else {
#pragma unroll
        for (int s = 0; s < 4; ++s)
#pragma unroll
          for (int r = 0; r < 4; ++r) {
            const int pg = p0 + s * 16 + quad * 4 + r;
            const float e = fexp2(t4[s][r] * CSC);
            ps[s][r] = (pg > qg) ? 0.f : e;
          }
      }

      ushort* pw = pbuf[wave] + lm * 64;
#pragma unroll
      for (int s = 0; s < 4; ++s) {
        uint2 pk;
        pk.x = (uint)f2bf(ps[s][0]) | ((uint)f2bf(ps[s][1]) << 16);
        pk.y = (uint)f2bf(ps[s][2]) | ((uint)f2bf(ps[s][3]) << 16);
        *(uint2*)(pw + ((((2 * s + (quad >> 1)) ^ psw) & 7) << 3) +
                  ((quad & 1) << 2)) = pk;
      }

      const ushort* vbuf = vt[it & 1];
      __builtin_amdgcn_s_setprio(1);
#pragma unroll
      for (int kc = 0; kc < 2; ++kc) {
        short8 pa = *(const short8*)(pw + ((((kc * 4 + quad) ^ psw) & 7) << 3));
        lacc = MFMA16(pa, vone, lacc);
#pragma unroll
        for (int c = 0; c < 4; ++c) {
          const int hrow = c * 16 + lm;
          const int fh = ((hrow >> 3) ^ hrow) & 7;
          short8 vb = *(const short8*)(
              vbuf + hrow * 64 + ((((4 * kc + quad) ^ fh) & 7) << 3));
          accz[c] = MFMA16(pa, vb, accz[c]);
        }
      }
      __builtin_amdgcn_s_setprio(0);

      if (more) {
        ushort* nbuf = vt[(it + 1) & 1];
        vt_write8(nbuf, h0, hsw, plb, nv0);
        vt_write8(nbuf, h0, hsw, plb + 32, nv1);
      }
    }

#pragma unroll
    for (int r = 0; r < 4; ++r) {
      const float inv = 1.f / lacc[r];
#pragma unroll
      for (int c = 0; c < 4; ++c)
        QKV[qcol + (size_t)(qrow + quad * 4 + r) * LD + c * 16 + lm] =
            f2bf(accz[c][r] * inv);
    }
  }
}

extern "C" void kernel_launch(void* const* d_in, const int* in_sizes, int n_in,
                              void* d_out, int out_size, void* d_ws, size_t ws_size,
                              hipStream_t stream) {
  (void)in_sizes; (void)n_in; (void)out_size; (void)ws_size;
  const float* x  = (const float*)d_in[0];   // (4,2048,1024) = (8192,1024)
  const float* wk = (const float*)d_in[1];   // (16,64,1024) flat (1024,1024)
  const float* wq = (const float*)d_in[2];
  const float* wv = (const float*)d_in[3];
  const float* wo = (const float*)d_in[4];   // (1024,1024)
  float* out = (float*)d_out;

  const size_t WSZ = (size_t)1024 * 1024;
  ushort* wqkv_b = (ushort*)d_ws;            // rows: 0..1023 Q, 1024.. K, 2048.. V
  ushort* wo_b = wqkv_b + 3 * WSZ;
  ushort* QKV = wo_b + WSZ;                  // 8192 x 3072
  ushort* xb = (ushort*)d_out;               // bf16 x in d_out (16 of 32 MB);
                                             // dead before out-proj writes

  // Fused converts: 4*(1M/4) + (8M/4) = 3145728 float4s = 12288 blocks exact.
  convert_all_kernel<<<12288, 256, 0, stream>>>(wq, wk, wv, wo, x,
                                                wqkv_b, wo_b, xb);

  // All-batch QKV projection: 2-buffer pipelined 128x128, 2 blocks/CU.
  // Grid 24 N x 64 M = 1536; XCD remap cpx=3.
  gemm_kernel<__hip_bfloat16><<<1536, 256, 0, stream>>>(
      xb, 1024, wqkv_b, 1024, (__hip_bfloat16*)QKV, 3072, 1024, 3);

  flash4_kernel<<<1024, 256, 0, stream>>>(QKV);

  // Out projection: Z (QKV cols 0..1023) * Wo^T -> fp32 out.
  gemm_kernel<float><<<512, 256, 0, stream>>>(
      QKV, 3072, wo_b, 1024, out, 1024, 1024, 1);
}